// Round 8
// baseline (1786.972 us; speedup 1.0000x reference)
//
#include <hip/hip_runtime.h>
#include <math.h>

#define NB 16
#define NC 256
#define NP 4096      // 64*64
#define NHEADS 8
#define NDH 32
#define NBH 128
#define NFF 1024
#define CEPS 1e-5f

typedef short s16x8 __attribute__((ext_vector_type(8)));
typedef float f32x4 __attribute__((ext_vector_type(4)));

// ---------------- diagnostic fill (guard trip) ----------------
__global__ __launch_bounds__(256) void diag_fill(float* __restrict__ out, float val, int n)
{
    int i = blockIdx.x * 256 + threadIdx.x;
    if (i < n) out[i] = val;
}

// ---------------- bf16 split helpers ----------------
__device__ inline unsigned short f2bf(float f) {
    unsigned u = __float_as_uint(f);
    return (unsigned short)((u + 0x7FFFu + ((u >> 16) & 1u)) >> 16);
}
__device__ inline float bf2f(unsigned short h) { return __uint_as_float(((unsigned)h) << 16); }
__device__ inline void split2(float f, unsigned short& hi, unsigned short& lo) {
    hi = f2bf(f);
    lo = f2bf(f - bf2f(hi));
}
// packed: (hi<<16)|lo
__device__ inline unsigned pack_hl(float f) {
    unsigned short h, lo; split2(f, h, lo);
    return ((unsigned)h << 16) | (unsigned)lo;
}
__device__ inline float packf(float f) { return __uint_as_float(pack_hl(f)); }

// ---------------- channel layer norm -> PACKED xn ----------------
__global__ __launch_bounds__(256) void cln_kernel(
    const float* __restrict__ x, const float* __restrict__ g, const float* __restrict__ bc,
    float* __restrict__ xn)
{
    int gp = blockIdx.x * 256 + threadIdx.x;
    int b = gp >> 12, p = gp & 4095;
    const float* src = x + (size_t)b * NC * NP + p;
    double s = 0.0, s2 = 0.0;
    for (int c = 0; c < NC; c++) { float v = src[(size_t)c * NP]; s += v; s2 += (double)v * v; }
    double mean = s * (1.0 / NC);
    double var = s2 * (1.0 / NC) - mean * mean;
    float rs = (float)(1.0 / sqrt(var + (double)CEPS));
    float mf = (float)mean;
    float* dst = xn + (size_t)b * NC * NP + p;
    for (int c = 0; c < NC; c++)
        dst[(size_t)c * NP] = packf((src[(size_t)c * NP] - mf) * rs * g[c] + bc[c]);
}

// ---------------- split-bf16 MFMA GEMM: 128o x 256p tile, 8 waves, K-step 32 ----------
// B-input PACKED hi/lo uint32; weights raw fp32. Reg-staged prefetch pipeline (T14):
//   store_lds(cur regs) -> barrier -> issue loads(k+1) -> frag reads + MFMA
template<bool PACKO>
__global__ __launch_bounds__(512, 4) void gemm_mfma(
    const float* __restrict__ inA, int sA, int C1,
    const float* __restrict__ inB, int sB, int Ctot,
    const float* __restrict__ Wt, const float* __restrict__ bias,
    const float* __restrict__ resid, float* __restrict__ out, int sO, int O)
{
    __shared__ __align__(16) unsigned short Ah[128 * 32], Al[128 * 32];
    __shared__ __align__(16) unsigned short Bh[256 * 32], Bl[256 * 32];
    char* cAh = (char*)Ah; char* cAl = (char*)Al;
    char* cBh = (char*)Bh; char* cBl = (char*)Bl;

    const int b = blockIdx.z;
    const int o0 = blockIdx.y * 128, p0 = blockIdx.x * 256;
    const int t = threadIdx.x;
    const int l = t & 63, w = t >> 6;
    const int wr = w >> 2, wc = w & 3;
    const int g = l >> 4, l15 = l & 15;
    const int slotl = (l & 3) ^ ((l >> 2) & 3);

    f32x4 acc[4][4];
    #pragma unroll
    for (int m = 0; m < 4; m++)
        #pragma unroll
        for (int n = 0; n < 4; n++) acc[m][n] = (f32x4){0.f, 0.f, 0.f, 0.f};

    // A-stage mapping: 128 rows x 32 k, 8 elems/thread
    const int arow = t >> 2;
    const int ak8 = (t & 3) * 8;
    const int aslot = (arow & 3) ^ ((arow >> 2) & 3);
    const int aoff = arow * 64 + ((((ak8 >> 3)) ^ aslot) << 4);
    // B-stage mapping: 256 rows(p) x 32 k, 16 elems/thread (8 k-pairs)
    const int bp = t & 255;
    const int bhalfk = t >> 8;
    const int bslot = (bp & 3) ^ ((bp >> 2) & 3);

    // prefetch registers
    float4 pa0, pa1;
    unsigned pb[16];

    #define LOAD_TILE(K0)                                                                 \
    {                                                                                     \
        const float* wsrc = Wt + (size_t)(o0 + arow) * Ctot + (K0) + ak8;                 \
        pa0 = *(const float4*)(wsrc);                                                     \
        pa1 = *(const float4*)(wsrc + 4);                                                 \
        _Pragma("unroll")                                                                 \
        for (int q = 0; q < 8; q++) {                                                     \
            int c2 = bhalfk * 16 + q * 2;                                                 \
            int cc = (K0) + c2;                                                           \
            const float* srcp = (cc < C1) ? inA + ((size_t)b * sA + cc) * (size_t)NP      \
                                          : inB + ((size_t)b * sB + (cc - C1)) * (size_t)NP; \
            pb[2 * q]     = __float_as_uint(srcp[p0 + bp]);                               \
            pb[2 * q + 1] = __float_as_uint(srcp[(size_t)NP + p0 + bp]);                  \
        }                                                                                 \
    }

    LOAD_TILE(0)

    for (int k0 = 0; k0 < Ctot; k0 += 32) {
        if (k0) __syncthreads();            // previous tile fully consumed
        // ---- store LDS from prefetch regs ----
        {
            ushort4 h0, l0, h1, l1;
            split2(pa0.x, h0.x, l0.x); split2(pa0.y, h0.y, l0.y);
            split2(pa0.z, h0.z, l0.z); split2(pa0.w, h0.w, l0.w);
            split2(pa1.x, h1.x, l1.x); split2(pa1.y, h1.y, l1.y);
            split2(pa1.z, h1.z, l1.z); split2(pa1.w, h1.w, l1.w);
            *(ushort4*)(cAh + aoff) = h0; *(ushort4*)(cAh + aoff + 8) = h1;
            *(ushort4*)(cAl + aoff) = l0; *(ushort4*)(cAl + aoff + 8) = l1;
            #pragma unroll
            for (int q = 0; q < 8; q++) {
                int c2 = bhalfk * 16 + q * 2;
                unsigned u0 = pb[2 * q], u1 = pb[2 * q + 1];
                unsigned hp = __builtin_amdgcn_perm(u1, u0, 0x07060302u);
                unsigned lp = __builtin_amdgcn_perm(u1, u0, 0x05040100u);
                int off = bp * 64 + ((((c2 >> 3)) ^ bslot) << 4) + (c2 & 7) * 2;
                *(unsigned*)(cBh + off) = hp;
                *(unsigned*)(cBl + off) = lp;
            }
        }
        __syncthreads();
        // ---- issue next tile's loads (latency hides under MFMA below) ----
        if (k0 + 32 < Ctot) LOAD_TILE(k0 + 32)

        // ---- fragments + MFMA ----
        s16x8 ah[4], al[4];
        #pragma unroll
        for (int m = 0; m < 4; m++) {
            int ao = (wr * 64 + m * 16 + l15) * 64 + ((g ^ slotl) << 4);
            ah[m] = *(const s16x8*)(cAh + ao);
            al[m] = *(const s16x8*)(cAl + ao);
        }
        #pragma unroll
        for (int n = 0; n < 4; n++) {
            int bo = (wc * 64 + n * 16 + l15) * 64 + ((g ^ slotl) << 4);
            s16x8 bh = *(const s16x8*)(cBh + bo);
            s16x8 bl = *(const s16x8*)(cBl + bo);
            #pragma unroll
            for (int m = 0; m < 4; m++) {
                acc[m][n] = __builtin_amdgcn_mfma_f32_16x16x32_bf16(ah[m], bh, acc[m][n], 0, 0, 0);
                acc[m][n] = __builtin_amdgcn_mfma_f32_16x16x32_bf16(ah[m], bl, acc[m][n], 0, 0, 0);
                acc[m][n] = __builtin_amdgcn_mfma_f32_16x16x32_bf16(al[m], bh, acc[m][n], 0, 0, 0);
            }
        }
    }
    #undef LOAD_TILE

    // ---- epilogue: D[row=(l>>4)*4+r][col=l&15] ----
    #pragma unroll
    for (int m = 0; m < 4; m++) {
        #pragma unroll
        for (int r = 0; r < 4; r++) {
            int orow = o0 + wr * 64 + m * 16 + g * 4 + r;
            float bs = bias ? bias[orow] : 0.f;
            #pragma unroll
            for (int n = 0; n < 4; n++) {
                int pcol = p0 + wc * 64 + n * 16 + l15;
                float v = acc[m][n][r] + bs;
                if (resid) v += resid[((size_t)b * O + orow) * (size_t)NP + pcol];
                out[((size_t)b * sO + orow) * (size_t)NP + pcol] = PACKO ? packf(v) : v;
            }
        }
    }
}

// ---------------- l2norm along W for q and k rows; emit |row|-sums ----------------
__global__ __launch_bounds__(256) void l2norm_kernel(
    float* __restrict__ qkv, float* __restrict__ qrow, float* __restrict__ kheight)
{
    int r = blockIdx.x * 4 + (threadIdx.x >> 6);
    int lane = threadIdx.x & 63;
    int which = r >> 18;
    int rr = r & 262143;
    int bh = rr >> 11;
    int c = (rr >> 6) & 31;
    int h = rr & 63;
    int b = bh >> 3, head = bh & 7;
    int ch = which * 256 + head * 32 + c;
    float* p = qkv + ((size_t)b * 768 + ch) * NP + h * 64 + lane;
    float v = *p;
    float ss = v * v, as = fabsf(v);
    for (int off = 32; off; off >>= 1) { ss += __shfl_xor(ss, off); as += __shfl_xor(as, off); }
    float n = sqrtf(ss);
    float inv = 1.f / fmaxf(n, 1e-12f);
    *p = v * inv;
    if (lane == 0) {
        float s = as * inv;
        if (which == 0) qrow[rr] = s; else kheight[rr] = s;
    }
}

__global__ void qprobe_kernel(const float* __restrict__ qrow, float* __restrict__ qprobe)
{
    int i = blockIdx.x * 64 + threadIdx.x;
    double s = 0.0;
    for (int h = 0; h < 64; h++) s += qrow[(size_t)i * 64 + h];
    qprobe[i] = (float)s;
}

// ---------------- scores + top-k rows/cols + gather k/v ----------------
__global__ __launch_bounds__(64) void select_kernel(
    const float* __restrict__ qkv, const float* __restrict__ qprobe,
    const float* __restrict__ kheight,
    float* __restrict__ ksel, float* __restrict__ vsel)
{
    const int bh = blockIdx.x;
    const int b = bh >> 3, head = bh & 7;
    const int lane = threadIdx.x;
    __shared__ int hs[8], wsl[8];
    __shared__ float qp[32];
    if (lane < 32) qp[lane] = qprobe[bh * 32 + lane];
    __syncthreads();
    double scd = 0.0;
    for (int c = 0; c < 32; c++) scd += (double)qp[c] * kheight[((size_t)bh * 32 + c) * 64 + lane];
    float sc = (float)scd;
    for (int it = 0; it < 8; it++) {
        float v = sc; int id = lane;
        for (int off = 32; off; off >>= 1) {
            float ov = __shfl_xor(v, off); int oi = __shfl_xor(id, off);
            if (ov > v || (ov == v && oi < id)) { v = ov; id = oi; }
        }
        if (lane == 0) hs[it] = id;
        if (lane == id) sc = -3.4e38f;
    }
    __syncthreads();
    const float* kbase = qkv + ((size_t)b * 768 + 256 + head * 32) * NP;
    double sc2d = 0.0;
    for (int c = 0; c < 32; c++) {
        float kw = 0.f;
        for (int hi = 0; hi < 8; hi++)
            kw += fabsf(kbase[(size_t)c * NP + hs[hi] * 64 + lane]);
        sc2d += (double)qp[c] * kw;
    }
    float sc2 = (float)sc2d;
    for (int it = 0; it < 8; it++) {
        float v = sc2; int id = lane;
        for (int off = 32; off; off >>= 1) {
            float ov = __shfl_xor(v, off); int oi = __shfl_xor(id, off);
            if (ov > v || (ov == v && oi < id)) { v = ov; id = oi; }
        }
        if (lane == 0) wsl[it] = id;
        if (lane == id) sc2 = -3.4e38f;
    }
    __syncthreads();
    const float* vbase = qkv + ((size_t)b * 768 + 512 + head * 32) * NP;
    int hi = lane >> 3, wi = lane & 7;
    int hh = hs[hi], ww = wsl[wi];
    for (int d = 0; d < 32; d++) {
        ksel[((size_t)bh * 64 + lane) * 32 + d] = kbase[(size_t)d * NP + hh * 64 + ww];
        vsel[((size_t)bh * 64 + lane) * 32 + d] = vbase[(size_t)d * NP + hh * 64 + ww];
    }
}

// ---------------- attention: in-place over q slot; writes PACKED ctx ----------------
__global__ __launch_bounds__(256) void attn_kernel(
    float* __restrict__ qkv, const float* __restrict__ ksel, const float* __restrict__ vsel)
{
    __shared__ __align__(16) float ks[64][32];
    __shared__ __align__(16) float vs[64][32];
    int bh = blockIdx.y, b = bh >> 3, head = bh & 7;
    int t = threadIdx.x;
    const float* kb = ksel + (size_t)bh * 2048;
    const float* vb = vsel + (size_t)bh * 2048;
    for (int i = 0; i < 8; i++) {
        ((float*)ks)[t + i * 256] = kb[t + i * 256];
        ((float*)vs)[t + i * 256] = vb[t + i * 256];
    }
    __syncthreads();
    int p = blockIdx.x * 256 + t;
    float* qb = qkv + ((size_t)b * 768 + head * 32) * NP + p;
    float q[32];
    #pragma unroll
    for (int d = 0; d < 32; d++) q[d] = qb[(size_t)d * NP];
    float s[64], m = -3.4e38f;
    for (int j = 0; j < 64; j++) {
        float dot = 0.f;
        #pragma unroll
        for (int d = 0; d < 32; d++) dot += q[d] * ks[j][d];
        s[j] = dot; m = fmaxf(m, dot);
    }
    float den = 0.f;
    for (int j = 0; j < 64; j++) { float e = expf(s[j] - m); s[j] = e; den += e; }
    float o[32] = {};
    for (int j = 0; j < 64; j++) {
        float a = s[j];
        #pragma unroll
        for (int d = 0; d < 32; d++) o[d] += a * vs[j][d];
    }
    float r = 1.f / den;
    #pragma unroll
    for (int d = 0; d < 32; d++) qb[(size_t)d * NP] = packf(o[d] * r);
}

// ---------------- depthwise 3x3 on x; PACKED strided output planes ----------------
__global__ __launch_bounds__(256) void dwconv_kernel(
    const float* __restrict__ in, const float* __restrict__ w, const float* __restrict__ bias,
    float* __restrict__ out, int Cn, int sO)
{
    __shared__ __align__(16) float pl[64][64];
    int bcb = blockIdx.x;
    int b = bcb / Cn, c = bcb % Cn;
    const float* src = in + (size_t)bcb * NP;
    float* dst = out + ((size_t)b * sO + c) * NP;
    int t = threadIdx.x;
    for (int i = 0; i < 16; i++) { int pix = t + i * 256; pl[pix >> 6][pix & 63] = src[pix]; }
    float w9[9];
    #pragma unroll
    for (int k = 0; k < 9; k++) w9[k] = w[c * 9 + k];
    float bsv = bias[c];
    __syncthreads();
    for (int i = 0; i < 16; i++) {
        int pix = t + i * 256; int y = pix >> 6, xx = pix & 63;
        float acc = bsv;
        #pragma unroll
        for (int dy = 0; dy < 3; dy++) {
            int yy = y + dy - 1; if (yy < 0 || yy > 63) continue;
            #pragma unroll
            for (int dx = 0; dx < 3; dx++) {
                int x2 = xx + dx - 1; if (x2 < 0 || x2 > 63) continue;
                acc += w9[dy * 3 + dx] * pl[yy][x2];
            }
        }
        dst[pix] = packf(acc);
    }
}

__device__ inline float gelu_exact(float x) {
    return 0.5f * x * (1.f + erff(x * 0.70710678118654752f));
}

__device__ inline void block_reduce2(double& s, double& s2, double* red, int t)
{
    __syncthreads();
    red[t] = s; red[256 + t] = s2;
    __syncthreads();
    for (int st = 128; st; st >>= 1) {
        if (t < st) { red[t] += red[t + st]; red[256 + t] += red[256 + t + st]; }
        __syncthreads();
    }
    s = red[0]; s2 = red[256];
}

// ---------------- fused FF: h = gelu(IN(h)); h += gelu(IN(dwconv3(h))); PACKED out ----
__global__ __launch_bounds__(256) void ff_fused_kernel(
    float* __restrict__ h, const float* __restrict__ w, const float* __restrict__ bias)
{
    __shared__ __align__(16) float pl[64][64];
    __shared__ double red[512];
    int plane = blockIdx.x;
    int c = plane & (NFF - 1);
    size_t base = (size_t)plane * NP;
    int t = threadIdx.x;
    float v[16]; double s = 0.0, s2 = 0.0;
    for (int i = 0; i < 16; i++) { float x = h[base + t + i * 256]; v[i] = x; s += x; s2 += (double)x * x; }
    block_reduce2(s, s2, red, t);
    double mean = s * (1.0 / NP);
    double var = s2 * (1.0 / NP) - mean * mean;
    float rs = (float)(1.0 / sqrt(var + (double)CEPS));
    float mf = (float)mean;
    for (int i = 0; i < 16; i++) {
        float gx = gelu_exact((v[i] - mf) * rs);
        v[i] = gx;
        int pix = t + i * 256;
        pl[pix >> 6][pix & 63] = gx;
    }
    __syncthreads();
    float w9[9];
    #pragma unroll
    for (int k = 0; k < 9; k++) w9[k] = w[c * 9 + k];
    float bsv = bias[c];
    float tv[16]; s = 0.0; s2 = 0.0;
    for (int i = 0; i < 16; i++) {
        int pix = t + i * 256; int y = pix >> 6, xx = pix & 63;
        float acc = bsv;
        #pragma unroll
        for (int dy = 0; dy < 3; dy++) {
            int yy = y + dy - 1; if (yy < 0 || yy > 63) continue;
            #pragma unroll
            for (int dx = 0; dx < 3; dx++) {
                int x2 = xx + dx - 1; if (x2 < 0 || x2 > 63) continue;
                acc += w9[dy * 3 + dx] * pl[yy][x2];
            }
        }
        tv[i] = acc; s += acc; s2 += (double)acc * acc;
    }
    block_reduce2(s, s2, red, t);
    double mean2 = s * (1.0 / NP);
    double var2 = s2 * (1.0 / NP) - mean2 * mean2;
    float rs2 = (float)(1.0 / sqrt(var2 + (double)CEPS));
    float mf2 = (float)mean2;
    for (int i = 0; i < 16; i++) {
        int pix = t + i * 256;
        float o = v[i] + gelu_exact((tv[i] - mf2) * rs2);
        h[base + pix] = packf(o);
    }
}

// ---------------- final instance norm in place on d_out ----------------
__global__ __launch_bounds__(256) void in_final_kernel(float* __restrict__ y)
{
    __shared__ double red[512];
    size_t base = (size_t)blockIdx.x * NP;
    int t = threadIdx.x;
    float v[16]; double s = 0.0, s2 = 0.0;
    for (int i = 0; i < 16; i++) { float x = y[base + t + i * 256]; v[i] = x; s += x; s2 += (double)x * x; }
    block_reduce2(s, s2, red, t);
    double mean = s * (1.0 / NP);
    double var = s2 * (1.0 / NP) - mean * mean;
    float rs = (float)(1.0 / sqrt(var + (double)CEPS));
    float mf = (float)mean;
    for (int i = 0; i < 16; i++)
        y[base + t + i * 256] = (v[i] - mf) * rs;
}

extern "C" void kernel_launch(void* const* d_in, const int* in_sizes, int n_in,
                              void* d_out, int out_size, void* d_ws, size_t ws_size,
                              hipStream_t stream)
{
    const float* x      = (const float*)d_in[0];
    const float* g      = (const float*)d_in[1];
    const float* bc     = (const float*)d_in[2];
    const float* w_qkv  = (const float*)d_in[3];
    const float* w_out  = (const float*)d_in[4];
    const float* b_out  = (const float*)d_in[5];
    const float* w_dw   = (const float*)d_in[6];
    const float* b_dw   = (const float*)d_in[7];
    const float* w_comb = (const float*)d_in[8];
    const float* b_comb = (const float*)d_in[9];
    const float* w_ff1  = (const float*)d_in[10];
    const float* b_ff1  = (const float*)d_in[11];
    const float* w_ffdw = (const float*)d_in[12];
    const float* b_ffdw = (const float*)d_in[13];
    const float* w_ff2  = (const float*)d_in[14];
    const float* b_ff2  = (const float*)d_in[15];
    float* out = (float*)d_out;
    float* ws  = (float*)d_ws;

    const size_t S = (size_t)NB * NC * NP;   // 16,777,216 floats (64 MiB)
    // ws plan (exactly 4S = 256 MiB):
    //   ws[0,S)  : xn packed (1-2) -> smalls (3-6) -> dead
    //   ws[S,4S) : qkv fp32; packed ctx in q-planes; attnb(packed) k-planes; convb(packed) v-planes
    //   d_out    : attn_out packed scratch (9-10), final output (12-13)
    //   ws[0,4S) : h1 fp32 (10), packed in place by ff_fused (11)
    float* xn    = ws;
    float* qkv   = ws + S;
    float* h1    = ws;
    float* Fbuf  = out;
    float* attnb = qkv + (size_t)256 * NP;
    float* convb = qkv + (size_t)512 * NP;
    float* qrow    = ws;
    float* qprobe  = qrow + 262144;
    float* kheight = qprobe + 4096;
    float* kselb   = kheight + 262144;
    float* vselb   = kselb + 262144;

    size_t need = 4 * S * sizeof(float);
    if (ws_size < need) {
        float val = 1024.0f + (float)(ws_size >> 20);
        diag_fill<<<(out_size + 255) / 256, 256, 0, stream>>>(out, val, out_size);
        return;
    }

    // 1. channel layer norm -> packed xn
    cln_kernel<<<256, 256, 0, stream>>>(x, g, bc, xn);
    // 2. qkv = W_qkv * xn  (O=768, fp32 out)
    gemm_mfma<false><<<dim3(16, 6, NB), 512, 0, stream>>>(xn, 256, 256, nullptr, 0, 256,
                                                          w_qkv, nullptr, nullptr, qkv, 768, 768);
    // 3. l2norm + row sums (fp32, in place)
    l2norm_kernel<<<131072, 256, 0, stream>>>(qkv, qrow, kheight);
    // 4. q_probe
    qprobe_kernel<<<64, 64, 0, stream>>>(qrow, qprobe);
    // 5. top-k + gather
    select_kernel<<<NBH, 64, 0, stream>>>(qkv, qprobe, kheight, kselb, vselb);
    // 6. attention (packed ctx -> q-planes)
    attn_kernel<<<dim3(16, NBH), 256, 0, stream>>>(qkv, kselb, vselb);
    // 7. attn_branch = W_out * ctx + b_out -> k-planes (packed)
    gemm_mfma<true><<<dim3(16, 2, NB), 512, 0, stream>>>(qkv, 768, 256, nullptr, 0, 256,
                                                         w_out, b_out, nullptr, attnb, 768, 256);
    // 8. conv branch -> v-planes (packed)
    dwconv_kernel<<<NB * NC, 256, 0, stream>>>(x, w_dw, b_dw, convb, NC, 768);
    // 9. attn_out = W_comb * [attnb; convb] + b_comb + x -> d_out (packed)
    gemm_mfma<true><<<dim3(16, 2, NB), 512, 0, stream>>>(attnb, 768, 256, convb, 768, 512,
                                                         w_comb, b_comb, x, Fbuf, 256, 256);
    // 10. h1 = W_ff1 * attn_out + b_ff1 -> ws[0,4S) fp32
    gemm_mfma<false><<<dim3(16, 8, NB), 512, 0, stream>>>(Fbuf, 256, 256, nullptr, 0, 256,
                                                          w_ff1, b_ff1, nullptr, h1, 1024, 1024);
    // 11. fused FF (packed in place)
    ff_fused_kernel<<<NB * NFF, 256, 0, stream>>>(h1, w_ffdw, b_ffdw);
    // 12. y = W_ff2 * h1 + b_ff2 -> d_out fp32
    gemm_mfma<false><<<dim3(16, 2, NB), 512, 0, stream>>>(h1, 1024, 1024, nullptr, 0, 1024,
                                                          w_ff2, b_ff2, nullptr, out, 256, 256);
    // 13. final instance norm
    in_final_kernel<<<NB * NC, 256, 0, stream>>>(out);
}

// Round 9
// 1155.641 us; speedup vs baseline: 1.5463x; 1.5463x over previous
//
#include <hip/hip_runtime.h>
#include <math.h>

#define NB 16
#define NC 256
#define NP 4096      // 64*64
#define NHEADS 8
#define NDH 32
#define NBH 128
#define NFF 1024
#define CEPS 1e-5f

typedef short s16x8 __attribute__((ext_vector_type(8)));
typedef float f32x4 __attribute__((ext_vector_type(4)));

// ---------------- diagnostic fill (guard trip) ----------------
__global__ __launch_bounds__(256) void diag_fill(float* __restrict__ out, float val, int n)
{
    int i = blockIdx.x * 256 + threadIdx.x;
    if (i < n) out[i] = val;
}

// ---------------- bf16 split helpers ----------------
__device__ inline unsigned short f2bf(float f) {
    unsigned u = __float_as_uint(f);
    return (unsigned short)((u + 0x7FFFu + ((u >> 16) & 1u)) >> 16);
}
__device__ inline float bf2f(unsigned short h) { return __uint_as_float(((unsigned)h) << 16); }
__device__ inline void split2(float f, unsigned short& hi, unsigned short& lo) {
    hi = f2bf(f);
    lo = f2bf(f - bf2f(hi));
}
// packed: (hi<<16)|lo
__device__ inline unsigned pack_hl(float f) {
    unsigned short h, lo; split2(f, h, lo);
    return ((unsigned)h << 16) | (unsigned)lo;
}
__device__ inline float packf(float f) { return __uint_as_float(pack_hl(f)); }

// ---------------- channel layer norm -> PACKED xn ----------------
__global__ __launch_bounds__(256) void cln_kernel(
    const float* __restrict__ x, const float* __restrict__ g, const float* __restrict__ bc,
    float* __restrict__ xn)
{
    int gp = blockIdx.x * 256 + threadIdx.x;
    int b = gp >> 12, p = gp & 4095;
    const float* src = x + (size_t)b * NC * NP + p;
    double s = 0.0, s2 = 0.0;
    for (int c = 0; c < NC; c++) { float v = src[(size_t)c * NP]; s += v; s2 += (double)v * v; }
    double mean = s * (1.0 / NC);
    double var = s2 * (1.0 / NC) - mean * mean;
    float rs = (float)(1.0 / sqrt(var + (double)CEPS));
    float mf = (float)mean;
    float* dst = xn + (size_t)b * NC * NP + p;
    for (int c = 0; c < NC; c++)
        dst[(size_t)c * NP] = packf((src[(size_t)c * NP] - mf) * rs * g[c] + bc[c]);
}

// ---------------- split-bf16 MFMA GEMM: 128o x 256p tile, 8 waves, K-step 32 ----------
// B-input PACKED hi/lo uint32; weights raw fp32. Reg-staged prefetch (T14) +
// XCD-batch swizzle (T1): batch = (lin&7) + 8*(rest>=npb) so each XCD owns 2 batches
// and one X-batch (4 MiB packed) is L2-resident across o-row re-reads.
// Requires gridDim.z == 16.
template<bool PACKO>
__global__ __launch_bounds__(512) void gemm_mfma(
    const float* __restrict__ inA, int sA, int C1,
    const float* __restrict__ inB, int sB, int Ctot,
    const float* __restrict__ Wt, const float* __restrict__ bias,
    const float* __restrict__ resid, float* __restrict__ out, int sO, int O)
{
    __shared__ __align__(16) unsigned short Ah[128 * 32], Al[128 * 32];
    __shared__ __align__(16) unsigned short Bh[256 * 32], Bl[256 * 32];
    char* cAh = (char*)Ah; char* cAl = (char*)Al;
    char* cBh = (char*)Bh; char* cBl = (char*)Bl;

    // ---- XCD-batch swizzle ----
    const unsigned npb = gridDim.x * gridDim.y;
    unsigned lin = blockIdx.x + gridDim.x * (blockIdx.y + gridDim.y * blockIdx.z);
    unsigned low = lin & 7u, rest = lin >> 3;
    unsigned high = (rest >= npb) ? 1u : 0u;
    unsigned idx = rest - high * npb;
    const int b = (int)(low + 8u * high);
    const int o0 = (int)(idx / gridDim.x) * 128, p0 = (int)(idx % gridDim.x) * 256;

    const int t = threadIdx.x;
    const int l = t & 63, w = t >> 6;
    const int wr = w >> 2, wc = w & 3;
    const int g = l >> 4, l15 = l & 15;
    const int slotl = (l & 3) ^ ((l >> 2) & 3);

    f32x4 acc[4][4];
    #pragma unroll
    for (int m = 0; m < 4; m++)
        #pragma unroll
        for (int n = 0; n < 4; n++) acc[m][n] = (f32x4){0.f, 0.f, 0.f, 0.f};

    // A-stage mapping: 128 rows x 32 k, 8 elems/thread
    const int arow = t >> 2;
    const int ak8 = (t & 3) * 8;
    const int aslot = (arow & 3) ^ ((arow >> 2) & 3);
    const int aoff = arow * 64 + ((((ak8 >> 3)) ^ aslot) << 4);
    // B-stage mapping: 256 rows(p) x 32 k, 16 elems/thread (8 k-pairs)
    const int bp = t & 255;
    const int bhalfk = t >> 8;
    const int bslot = (bp & 3) ^ ((bp >> 2) & 3);

    // prefetch registers
    float4 pa0, pa1;
    unsigned pb[16];

    #define LOAD_TILE(K0)                                                                 \
    {                                                                                     \
        const float* wsrc = Wt + (size_t)(o0 + arow) * Ctot + (K0) + ak8;                 \
        pa0 = *(const float4*)(wsrc);                                                     \
        pa1 = *(const float4*)(wsrc + 4);                                                 \
        _Pragma("unroll")                                                                 \
        for (int q = 0; q < 8; q++) {                                                     \
            int c2 = bhalfk * 16 + q * 2;                                                 \
            int cc = (K0) + c2;                                                           \
            const float* srcp = (cc < C1) ? inA + ((size_t)b * sA + cc) * (size_t)NP      \
                                          : inB + ((size_t)b * sB + (cc - C1)) * (size_t)NP; \
            pb[2 * q]     = __float_as_uint(srcp[p0 + bp]);                               \
            pb[2 * q + 1] = __float_as_uint(srcp[(size_t)NP + p0 + bp]);                  \
        }                                                                                 \
    }

    LOAD_TILE(0)

    for (int k0 = 0; k0 < Ctot; k0 += 32) {
        if (k0) __syncthreads();            // previous tile fully consumed
        // ---- store LDS from prefetch regs ----
        {
            ushort4 h0, l0, h1, l1;
            split2(pa0.x, h0.x, l0.x); split2(pa0.y, h0.y, l0.y);
            split2(pa0.z, h0.z, l0.z); split2(pa0.w, h0.w, l0.w);
            split2(pa1.x, h1.x, l1.x); split2(pa1.y, h1.y, l1.y);
            split2(pa1.z, h1.z, l1.z); split2(pa1.w, h1.w, l1.w);
            *(ushort4*)(cAh + aoff) = h0; *(ushort4*)(cAh + aoff + 8) = h1;
            *(ushort4*)(cAl + aoff) = l0; *(ushort4*)(cAl + aoff + 8) = l1;
            #pragma unroll
            for (int q = 0; q < 8; q++) {
                int c2 = bhalfk * 16 + q * 2;
                unsigned u0 = pb[2 * q], u1 = pb[2 * q + 1];
                unsigned hp = __builtin_amdgcn_perm(u1, u0, 0x07060302u);
                unsigned lp = __builtin_amdgcn_perm(u1, u0, 0x05040100u);
                int off = bp * 64 + ((((c2 >> 3)) ^ bslot) << 4) + (c2 & 7) * 2;
                *(unsigned*)(cBh + off) = hp;
                *(unsigned*)(cBl + off) = lp;
            }
        }
        __syncthreads();
        // ---- issue next tile's loads (latency hides under MFMA below) ----
        if (k0 + 32 < Ctot) LOAD_TILE(k0 + 32)

        // ---- fragments + MFMA ----
        s16x8 ah[4], al[4];
        #pragma unroll
        for (int m = 0; m < 4; m++) {
            int ao = (wr * 64 + m * 16 + l15) * 64 + ((g ^ slotl) << 4);
            ah[m] = *(const s16x8*)(cAh + ao);
            al[m] = *(const s16x8*)(cAl + ao);
        }
        #pragma unroll
        for (int n = 0; n < 4; n++) {
            int bo = (wc * 64 + n * 16 + l15) * 64 + ((g ^ slotl) << 4);
            s16x8 bh = *(const s16x8*)(cBh + bo);
            s16x8 bl = *(const s16x8*)(cBl + bo);
            #pragma unroll
            for (int m = 0; m < 4; m++) {
                acc[m][n] = __builtin_amdgcn_mfma_f32_16x16x32_bf16(ah[m], bh, acc[m][n], 0, 0, 0);
                acc[m][n] = __builtin_amdgcn_mfma_f32_16x16x32_bf16(ah[m], bl, acc[m][n], 0, 0, 0);
                acc[m][n] = __builtin_amdgcn_mfma_f32_16x16x32_bf16(al[m], bh, acc[m][n], 0, 0, 0);
            }
        }
    }
    #undef LOAD_TILE

    // ---- epilogue: D[row=(l>>4)*4+r][col=l&15] ----
    #pragma unroll
    for (int m = 0; m < 4; m++) {
        #pragma unroll
        for (int r = 0; r < 4; r++) {
            int orow = o0 + wr * 64 + m * 16 + g * 4 + r;
            float bs = bias ? bias[orow] : 0.f;
            #pragma unroll
            for (int n = 0; n < 4; n++) {
                int pcol = p0 + wc * 64 + n * 16 + l15;
                float v = acc[m][n][r] + bs;
                if (resid) v += resid[((size_t)b * O + orow) * (size_t)NP + pcol];
                out[((size_t)b * sO + orow) * (size_t)NP + pcol] = PACKO ? packf(v) : v;
            }
        }
    }
}

// ---------------- l2norm along W for q and k rows; emit |row|-sums ----------------
__global__ __launch_bounds__(256) void l2norm_kernel(
    float* __restrict__ qkv, float* __restrict__ qrow, float* __restrict__ kheight)
{
    int r = blockIdx.x * 4 + (threadIdx.x >> 6);
    int lane = threadIdx.x & 63;
    int which = r >> 18;
    int rr = r & 262143;
    int bh = rr >> 11;
    int c = (rr >> 6) & 31;
    int h = rr & 63;
    int b = bh >> 3, head = bh & 7;
    int ch = which * 256 + head * 32 + c;
    float* p = qkv + ((size_t)b * 768 + ch) * NP + h * 64 + lane;
    float v = *p;
    float ss = v * v, as = fabsf(v);
    for (int off = 32; off; off >>= 1) { ss += __shfl_xor(ss, off); as += __shfl_xor(as, off); }
    float n = sqrtf(ss);
    float inv = 1.f / fmaxf(n, 1e-12f);
    *p = v * inv;
    if (lane == 0) {
        float s = as * inv;
        if (which == 0) qrow[rr] = s; else kheight[rr] = s;
    }
}

__global__ void qprobe_kernel(const float* __restrict__ qrow, float* __restrict__ qprobe)
{
    int i = blockIdx.x * 64 + threadIdx.x;
    double s = 0.0;
    for (int h = 0; h < 64; h++) s += qrow[(size_t)i * 64 + h];
    qprobe[i] = (float)s;
}

// ---------------- scores + top-k rows/cols + gather k/v ----------------
__global__ __launch_bounds__(64) void select_kernel(
    const float* __restrict__ qkv, const float* __restrict__ qprobe,
    const float* __restrict__ kheight,
    float* __restrict__ ksel, float* __restrict__ vsel)
{
    const int bh = blockIdx.x;
    const int b = bh >> 3, head = bh & 7;
    const int lane = threadIdx.x;
    __shared__ int hs[8], wsl[8];
    __shared__ float qp[32];
    if (lane < 32) qp[lane] = qprobe[bh * 32 + lane];
    __syncthreads();
    double scd = 0.0;
    for (int c = 0; c < 32; c++) scd += (double)qp[c] * kheight[((size_t)bh * 32 + c) * 64 + lane];
    float sc = (float)scd;
    for (int it = 0; it < 8; it++) {
        float v = sc; int id = lane;
        for (int off = 32; off; off >>= 1) {
            float ov = __shfl_xor(v, off); int oi = __shfl_xor(id, off);
            if (ov > v || (ov == v && oi < id)) { v = ov; id = oi; }
        }
        if (lane == 0) hs[it] = id;
        if (lane == id) sc = -3.4e38f;
    }
    __syncthreads();
    const float* kbase = qkv + ((size_t)b * 768 + 256 + head * 32) * NP;
    double sc2d = 0.0;
    for (int c = 0; c < 32; c++) {
        float kw = 0.f;
        for (int hi = 0; hi < 8; hi++)
            kw += fabsf(kbase[(size_t)c * NP + hs[hi] * 64 + lane]);
        sc2d += (double)qp[c] * kw;
    }
    float sc2 = (float)sc2d;
    for (int it = 0; it < 8; it++) {
        float v = sc2; int id = lane;
        for (int off = 32; off; off >>= 1) {
            float ov = __shfl_xor(v, off); int oi = __shfl_xor(id, off);
            if (ov > v || (ov == v && oi < id)) { v = ov; id = oi; }
        }
        if (lane == 0) wsl[it] = id;
        if (lane == id) sc2 = -3.4e38f;
    }
    __syncthreads();
    const float* vbase = qkv + ((size_t)b * 768 + 512 + head * 32) * NP;
    int hi = lane >> 3, wi = lane & 7;
    int hh = hs[hi], ww = wsl[wi];
    for (int d = 0; d < 32; d++) {
        ksel[((size_t)bh * 64 + lane) * 32 + d] = kbase[(size_t)d * NP + hh * 64 + ww];
        vsel[((size_t)bh * 64 + lane) * 32 + d] = vbase[(size_t)d * NP + hh * 64 + ww];
    }
}

// ---------------- attention: in-place over q slot; writes PACKED ctx ----------------
__global__ __launch_bounds__(256) void attn_kernel(
    float* __restrict__ qkv, const float* __restrict__ ksel, const float* __restrict__ vsel)
{
    __shared__ __align__(16) float ks[64][32];
    __shared__ __align__(16) float vs[64][32];
    int bh = blockIdx.y, b = bh >> 3, head = bh & 7;
    int t = threadIdx.x;
    const float* kb = ksel + (size_t)bh * 2048;
    const float* vb = vsel + (size_t)bh * 2048;
    for (int i = 0; i < 8; i++) {
        ((float*)ks)[t + i * 256] = kb[t + i * 256];
        ((float*)vs)[t + i * 256] = vb[t + i * 256];
    }
    __syncthreads();
    int p = blockIdx.x * 256 + t;
    float* qb = qkv + ((size_t)b * 768 + head * 32) * NP + p;
    float q[32];
    #pragma unroll
    for (int d = 0; d < 32; d++) q[d] = qb[(size_t)d * NP];
    float s[64], m = -3.4e38f;
    for (int j = 0; j < 64; j++) {
        float dot = 0.f;
        #pragma unroll
        for (int d = 0; d < 32; d++) dot += q[d] * ks[j][d];
        s[j] = dot; m = fmaxf(m, dot);
    }
    float den = 0.f;
    for (int j = 0; j < 64; j++) { float e = expf(s[j] - m); s[j] = e; den += e; }
    float o[32] = {};
    for (int j = 0; j < 64; j++) {
        float a = s[j];
        #pragma unroll
        for (int d = 0; d < 32; d++) o[d] += a * vs[j][d];
    }
    float r = 1.f / den;
    #pragma unroll
    for (int d = 0; d < 32; d++) qb[(size_t)d * NP] = packf(o[d] * r);
}

// ---------------- depthwise 3x3 on x; PACKED strided output planes ----------------
__global__ __launch_bounds__(256) void dwconv_kernel(
    const float* __restrict__ in, const float* __restrict__ w, const float* __restrict__ bias,
    float* __restrict__ out, int Cn, int sO)
{
    __shared__ __align__(16) float pl[64][64];
    int bcb = blockIdx.x;
    int b = bcb / Cn, c = bcb % Cn;
    const float* src = in + (size_t)bcb * NP;
    float* dst = out + ((size_t)b * sO + c) * NP;
    int t = threadIdx.x;
    for (int i = 0; i < 16; i++) { int pix = t + i * 256; pl[pix >> 6][pix & 63] = src[pix]; }
    float w9[9];
    #pragma unroll
    for (int k = 0; k < 9; k++) w9[k] = w[c * 9 + k];
    float bsv = bias[c];
    __syncthreads();
    for (int i = 0; i < 16; i++) {
        int pix = t + i * 256; int y = pix >> 6, xx = pix & 63;
        float acc = bsv;
        #pragma unroll
        for (int dy = 0; dy < 3; dy++) {
            int yy = y + dy - 1; if (yy < 0 || yy > 63) continue;
            #pragma unroll
            for (int dx = 0; dx < 3; dx++) {
                int x2 = xx + dx - 1; if (x2 < 0 || x2 > 63) continue;
                acc += w9[dy * 3 + dx] * pl[yy][x2];
            }
        }
        dst[pix] = packf(acc);
    }
}

__device__ inline float gelu_exact(float x) {
    return 0.5f * x * (1.f + erff(x * 0.70710678118654752f));
}

__device__ inline void block_reduce2(double& s, double& s2, double* red, int t)
{
    __syncthreads();
    red[t] = s; red[256 + t] = s2;
    __syncthreads();
    for (int st = 128; st; st >>= 1) {
        if (t < st) { red[t] += red[t + st]; red[256 + t] += red[256 + t + st]; }
        __syncthreads();
    }
    s = red[0]; s2 = red[256];
}

// ---------------- fused FF: h = gelu(IN(h)); h += gelu(IN(dwconv3(h))); PACKED out ----
__global__ __launch_bounds__(256) void ff_fused_kernel(
    float* __restrict__ h, const float* __restrict__ w, const float* __restrict__ bias)
{
    __shared__ __align__(16) float pl[64][64];
    __shared__ double red[512];
    int plane = blockIdx.x;
    int c = plane & (NFF - 1);
    size_t base = (size_t)plane * NP;
    int t = threadIdx.x;
    float v[16]; double s = 0.0, s2 = 0.0;
    for (int i = 0; i < 16; i++) { float x = h[base + t + i * 256]; v[i] = x; s += x; s2 += (double)x * x; }
    block_reduce2(s, s2, red, t);
    double mean = s * (1.0 / NP);
    double var = s2 * (1.0 / NP) - mean * mean;
    float rs = (float)(1.0 / sqrt(var + (double)CEPS));
    float mf = (float)mean;
    for (int i = 0; i < 16; i++) {
        float gx = gelu_exact((v[i] - mf) * rs);
        v[i] = gx;
        int pix = t + i * 256;
        pl[pix >> 6][pix & 63] = gx;
    }
    __syncthreads();
    float w9[9];
    #pragma unroll
    for (int k = 0; k < 9; k++) w9[k] = w[c * 9 + k];
    float bsv = bias[c];
    float tv[16]; s = 0.0; s2 = 0.0;
    for (int i = 0; i < 16; i++) {
        int pix = t + i * 256; int y = pix >> 6, xx = pix & 63;
        float acc = bsv;
        #pragma unroll
        for (int dy = 0; dy < 3; dy++) {
            int yy = y + dy - 1; if (yy < 0 || yy > 63) continue;
            #pragma unroll
            for (int dx = 0; dx < 3; dx++) {
                int x2 = xx + dx - 1; if (x2 < 0 || x2 > 63) continue;
                acc += w9[dy * 3 + dx] * pl[yy][x2];
            }
        }
        tv[i] = acc; s += acc; s2 += (double)acc * acc;
    }
    block_reduce2(s, s2, red, t);
    double mean2 = s * (1.0 / NP);
    double var2 = s2 * (1.0 / NP) - mean2 * mean2;
    float rs2 = (float)(1.0 / sqrt(var2 + (double)CEPS));
    float mf2 = (float)mean2;
    for (int i = 0; i < 16; i++) {
        int pix = t + i * 256;
        float o = v[i] + gelu_exact((tv[i] - mf2) * rs2);
        h[base + pix] = packf(o);
    }
}

// ---------------- final instance norm in place on d_out ----------------
__global__ __launch_bounds__(256) void in_final_kernel(float* __restrict__ y)
{
    __shared__ double red[512];
    size_t base = (size_t)blockIdx.x * NP;
    int t = threadIdx.x;
    float v[16]; double s = 0.0, s2 = 0.0;
    for (int i = 0; i < 16; i++) { float x = y[base + t + i * 256]; v[i] = x; s += x; s2 += (double)x * x; }
    block_reduce2(s, s2, red, t);
    double mean = s * (1.0 / NP);
    double var = s2 * (1.0 / NP) - mean * mean;
    float rs = (float)(1.0 / sqrt(var + (double)CEPS));
    float mf = (float)mean;
    for (int i = 0; i < 16; i++)
        y[base + t + i * 256] = (v[i] - mf) * rs;
}

extern "C" void kernel_launch(void* const* d_in, const int* in_sizes, int n_in,
                              void* d_out, int out_size, void* d_ws, size_t ws_size,
                              hipStream_t stream)
{
    const float* x      = (const float*)d_in[0];
    const float* g      = (const float*)d_in[1];
    const float* bc     = (const float*)d_in[2];
    const float* w_qkv  = (const float*)d_in[3];
    const float* w_out  = (const float*)d_in[4];
    const float* b_out  = (const float*)d_in[5];
    const float* w_dw   = (const float*)d_in[6];
    const float* b_dw   = (const float*)d_in[7];
    const float* w_comb = (const float*)d_in[8];
    const float* b_comb = (const float*)d_in[9];
    const float* w_ff1  = (const float*)d_in[10];
    const float* b_ff1  = (const float*)d_in[11];
    const float* w_ffdw = (const float*)d_in[12];
    const float* b_ffdw = (const float*)d_in[13];
    const float* w_ff2  = (const float*)d_in[14];
    const float* b_ff2  = (const float*)d_in[15];
    float* out = (float*)d_out;
    float* ws  = (float*)d_ws;

    const size_t S = (size_t)NB * NC * NP;   // 16,777,216 floats (64 MiB)
    // ws plan (exactly 4S = 256 MiB):
    //   ws[0,S)  : xn packed (1-2) -> smalls (3-6) -> dead
    //   ws[S,4S) : qkv fp32; packed ctx in q-planes; attnb(packed) k-planes; convb(packed) v-planes
    //   d_out    : attn_out packed scratch (9-10), final output (12-13)
    //   ws[0,4S) : h1 fp32 (10), packed in place by ff_fused (11)
    float* xn    = ws;
    float* qkv   = ws + S;
    float* h1    = ws;
    float* Fbuf  = out;
    float* attnb = qkv + (size_t)256 * NP;
    float* convb = qkv + (size_t)512 * NP;
    float* qrow    = ws;
    float* qprobe  = qrow + 262144;
    float* kheight = qprobe + 4096;
    float* kselb   = kheight + 262144;
    float* vselb   = kselb + 262144;

    size_t need = 4 * S * sizeof(float);
    if (ws_size < need) {
        float val = 1024.0f + (float)(ws_size >> 20);
        diag_fill<<<(out_size + 255) / 256, 256, 0, stream>>>(out, val, out_size);
        return;
    }

    // 1. channel layer norm -> packed xn
    cln_kernel<<<256, 256, 0, stream>>>(x, g, bc, xn);
    // 2. qkv = W_qkv * xn  (O=768, fp32 out)
    gemm_mfma<false><<<dim3(16, 6, NB), 512, 0, stream>>>(xn, 256, 256, nullptr, 0, 256,
                                                          w_qkv, nullptr, nullptr, qkv, 768, 768);
    // 3. l2norm + row sums (fp32, in place)
    l2norm_kernel<<<131072, 256, 0, stream>>>(qkv, qrow, kheight);
    // 4. q_probe
    qprobe_kernel<<<64, 64, 0, stream>>>(qrow, qprobe);
    // 5. top-k + gather
    select_kernel<<<NBH, 64, 0, stream>>>(qkv, qprobe, kheight, kselb, vselb);
    // 6. attention (packed ctx -> q-planes)
    attn_kernel<<<dim3(16, NBH), 256, 0, stream>>>(qkv, kselb, vselb);
    // 7. attn_branch = W_out * ctx + b_out -> k-planes (packed)
    gemm_mfma<true><<<dim3(16, 2, NB), 512, 0, stream>>>(qkv, 768, 256, nullptr, 0, 256,
                                                         w_out, b_out, nullptr, attnb, 768, 256);
    // 8. conv branch -> v-planes (packed)
    dwconv_kernel<<<NB * NC, 256, 0, stream>>>(x, w_dw, b_dw, convb, NC, 768);
    // 9. attn_out = W_comb * [attnb; convb] + b_comb + x -> d_out (packed)
    gemm_mfma<true><<<dim3(16, 2, NB), 512, 0, stream>>>(attnb, 768, 256, convb, 768, 512,
                                                         w_comb, b_comb, x, Fbuf, 256, 256);
    // 10. h1 = W_ff1 * attn_out + b_ff1 -> ws[0,4S) fp32
    gemm_mfma<false><<<dim3(16, 8, NB), 512, 0, stream>>>(Fbuf, 256, 256, nullptr, 0, 256,
                                                          w_ff1, b_ff1, nullptr, h1, 1024, 1024);
    // 11. fused FF (packed in place)
    ff_fused_kernel<<<NB * NFF, 256, 0, stream>>>(h1, w_ffdw, b_ffdw);
    // 12. y = W_ff2 * h1 + b_ff2 -> d_out fp32
    gemm_mfma<false><<<dim3(16, 2, NB), 512, 0, stream>>>(h1, 1024, 1024, nullptr, 0, 1024,
                                                          w_ff2, b_ff2, nullptr, out, 256, 256);
    // 13. final instance norm
    in_final_kernel<<<NB * NC, 256, 0, stream>>>(out);
}

// Round 10
// 1146.775 us; speedup vs baseline: 1.5583x; 1.0077x over previous
//
#include <hip/hip_runtime.h>
#include <math.h>

#define NB 16
#define NC 256
#define NP 4096      // 64*64
#define NHEADS 8
#define NDH 32
#define NBH 128
#define NFF 1024
#define CEPS 1e-5f

typedef short s16x8 __attribute__((ext_vector_type(8)));
typedef float f32x4 __attribute__((ext_vector_type(4)));

// ---------------- diagnostic fill (guard trip) ----------------
__global__ __launch_bounds__(256) void diag_fill(float* __restrict__ out, float val, int n)
{
    int i = blockIdx.x * 256 + threadIdx.x;
    if (i < n) out[i] = val;
}

// ---------------- bf16 split helpers ----------------
__device__ inline unsigned short f2bf(float f) {
    unsigned u = __float_as_uint(f);
    return (unsigned short)((u + 0x7FFFu + ((u >> 16) & 1u)) >> 16);
}
__device__ inline float bf2f(unsigned short h) { return __uint_as_float(((unsigned)h) << 16); }
__device__ inline void split2(float f, unsigned short& hi, unsigned short& lo) {
    hi = f2bf(f);
    lo = f2bf(f - bf2f(hi));
}
// packed: (hi<<16)|lo
__device__ inline unsigned pack_hl(float f) {
    unsigned short h, lo; split2(f, h, lo);
    return ((unsigned)h << 16) | (unsigned)lo;
}
__device__ inline float packf(float f) { return __uint_as_float(pack_hl(f)); }

// ---------------- channel layer norm -> PACKED xn ----------------
__global__ __launch_bounds__(256) void cln_kernel(
    const float* __restrict__ x, const float* __restrict__ g, const float* __restrict__ bc,
    float* __restrict__ xn)
{
    int gp = blockIdx.x * 256 + threadIdx.x;
    int b = gp >> 12, p = gp & 4095;
    const float* src = x + (size_t)b * NC * NP + p;
    double s = 0.0, s2 = 0.0;
    for (int c = 0; c < NC; c++) { float v = src[(size_t)c * NP]; s += v; s2 += (double)v * v; }
    double mean = s * (1.0 / NC);
    double var = s2 * (1.0 / NC) - mean * mean;
    float rs = (float)(1.0 / sqrt(var + (double)CEPS));
    float mf = (float)mean;
    float* dst = xn + (size_t)b * NC * NP + p;
    for (int c = 0; c < NC; c++)
        dst[(size_t)c * NP] = packf((src[(size_t)c * NP] - mf) * rs * g[c] + bc[c]);
}

// ---------------- split-bf16 MFMA GEMM: 128o x 256p tile, 8 waves, K-step 32 ----------
template<bool PACKO>
__global__ __launch_bounds__(512) void gemm_mfma(
    const float* __restrict__ inA, int sA, int C1,
    const float* __restrict__ inB, int sB, int Ctot,
    const float* __restrict__ Wt, const float* __restrict__ bias,
    const float* __restrict__ resid, float* __restrict__ out, int sO, int O)
{
    __shared__ __align__(16) unsigned short Ah[128 * 32], Al[128 * 32];
    __shared__ __align__(16) unsigned short Bh[256 * 32], Bl[256 * 32];
    char* cAh = (char*)Ah; char* cAl = (char*)Al;
    char* cBh = (char*)Bh; char* cBl = (char*)Bl;

    // ---- XCD-batch swizzle ----
    const unsigned npb = gridDim.x * gridDim.y;
    unsigned lin = blockIdx.x + gridDim.x * (blockIdx.y + gridDim.y * blockIdx.z);
    unsigned low = lin & 7u, rest = lin >> 3;
    unsigned high = (rest >= npb) ? 1u : 0u;
    unsigned idx = rest - high * npb;
    const int b = (int)(low + 8u * high);
    const int o0 = (int)(idx / gridDim.x) * 128, p0 = (int)(idx % gridDim.x) * 256;

    const int t = threadIdx.x;
    const int l = t & 63, w = t >> 6;
    const int wr = w >> 2, wc = w & 3;
    const int g = l >> 4, l15 = l & 15;
    const int slotl = (l & 3) ^ ((l >> 2) & 3);

    f32x4 acc[4][4];
    #pragma unroll
    for (int m = 0; m < 4; m++)
        #pragma unroll
        for (int n = 0; n < 4; n++) acc[m][n] = (f32x4){0.f, 0.f, 0.f, 0.f};

    const int arow = t >> 2;
    const int ak8 = (t & 3) * 8;
    const int aslot = (arow & 3) ^ ((arow >> 2) & 3);
    const int aoff = arow * 64 + ((((ak8 >> 3)) ^ aslot) << 4);
    const int bp = t & 255;
    const int bhalfk = t >> 8;
    const int bslot = (bp & 3) ^ ((bp >> 2) & 3);

    float4 pa0, pa1;
    unsigned pb[16];

    #define LOAD_TILE(K0)                                                                 \
    {                                                                                     \
        const float* wsrc = Wt + (size_t)(o0 + arow) * Ctot + (K0) + ak8;                 \
        pa0 = *(const float4*)(wsrc);                                                     \
        pa1 = *(const float4*)(wsrc + 4);                                                 \
        _Pragma("unroll")                                                                 \
        for (int q = 0; q < 8; q++) {                                                     \
            int c2 = bhalfk * 16 + q * 2;                                                 \
            int cc = (K0) + c2;                                                           \
            const float* srcp = (cc < C1) ? inA + ((size_t)b * sA + cc) * (size_t)NP      \
                                          : inB + ((size_t)b * sB + (cc - C1)) * (size_t)NP; \
            pb[2 * q]     = __float_as_uint(srcp[p0 + bp]);                               \
            pb[2 * q + 1] = __float_as_uint(srcp[(size_t)NP + p0 + bp]);                  \
        }                                                                                 \
    }

    LOAD_TILE(0)

    for (int k0 = 0; k0 < Ctot; k0 += 32) {
        if (k0) __syncthreads();
        {
            ushort4 h0, l0, h1, l1;
            split2(pa0.x, h0.x, l0.x); split2(pa0.y, h0.y, l0.y);
            split2(pa0.z, h0.z, l0.z); split2(pa0.w, h0.w, l0.w);
            split2(pa1.x, h1.x, l1.x); split2(pa1.y, h1.y, l1.y);
            split2(pa1.z, h1.z, l1.z); split2(pa1.w, h1.w, l1.w);
            *(ushort4*)(cAh + aoff) = h0; *(ushort4*)(cAh + aoff + 8) = h1;
            *(ushort4*)(cAl + aoff) = l0; *(ushort4*)(cAl + aoff + 8) = l1;
            #pragma unroll
            for (int q = 0; q < 8; q++) {
                int c2 = bhalfk * 16 + q * 2;
                unsigned u0 = pb[2 * q], u1 = pb[2 * q + 1];
                unsigned hp = __builtin_amdgcn_perm(u1, u0, 0x07060302u);
                unsigned lp = __builtin_amdgcn_perm(u1, u0, 0x05040100u);
                int off = bp * 64 + ((((c2 >> 3)) ^ bslot) << 4) + (c2 & 7) * 2;
                *(unsigned*)(cBh + off) = hp;
                *(unsigned*)(cBl + off) = lp;
            }
        }
        __syncthreads();
        if (k0 + 32 < Ctot) LOAD_TILE(k0 + 32)

        s16x8 ah[4], al[4];
        #pragma unroll
        for (int m = 0; m < 4; m++) {
            int ao = (wr * 64 + m * 16 + l15) * 64 + ((g ^ slotl) << 4);
            ah[m] = *(const s16x8*)(cAh + ao);
            al[m] = *(const s16x8*)(cAl + ao);
        }
        #pragma unroll
        for (int n = 0; n < 4; n++) {
            int bo = (wc * 64 + n * 16 + l15) * 64 + ((g ^ slotl) << 4);
            s16x8 bh = *(const s16x8*)(cBh + bo);
            s16x8 bl = *(const s16x8*)(cBl + bo);
            #pragma unroll
            for (int m = 0; m < 4; m++) {
                acc[m][n] = __builtin_amdgcn_mfma_f32_16x16x32_bf16(ah[m], bh, acc[m][n], 0, 0, 0);
                acc[m][n] = __builtin_amdgcn_mfma_f32_16x16x32_bf16(ah[m], bl, acc[m][n], 0, 0, 0);
                acc[m][n] = __builtin_amdgcn_mfma_f32_16x16x32_bf16(al[m], bh, acc[m][n], 0, 0, 0);
            }
        }
    }
    #undef LOAD_TILE

    #pragma unroll
    for (int m = 0; m < 4; m++) {
        #pragma unroll
        for (int r = 0; r < 4; r++) {
            int orow = o0 + wr * 64 + m * 16 + g * 4 + r;
            float bs = bias ? bias[orow] : 0.f;
            #pragma unroll
            for (int n = 0; n < 4; n++) {
                int pcol = p0 + wc * 64 + n * 16 + l15;
                float v = acc[m][n][r] + bs;
                if (resid) v += resid[((size_t)b * O + orow) * (size_t)NP + pcol];
                out[((size_t)b * sO + orow) * (size_t)NP + pcol] = PACKO ? packf(v) : v;
            }
        }
    }
}

// ---------------- l2norm along W for q and k rows; emit |row|-sums ----------------
__global__ __launch_bounds__(256) void l2norm_kernel(
    float* __restrict__ qkv, float* __restrict__ qrow, float* __restrict__ kheight)
{
    int r = blockIdx.x * 4 + (threadIdx.x >> 6);
    int lane = threadIdx.x & 63;
    int which = r >> 18;
    int rr = r & 262143;
    int bh = rr >> 11;
    int c = (rr >> 6) & 31;
    int h = rr & 63;
    int b = bh >> 3, head = bh & 7;
    int ch = which * 256 + head * 32 + c;
    float* p = qkv + ((size_t)b * 768 + ch) * NP + h * 64 + lane;
    float v = *p;
    float ss = v * v, as = fabsf(v);
    for (int off = 32; off; off >>= 1) { ss += __shfl_xor(ss, off); as += __shfl_xor(as, off); }
    float n = sqrtf(ss);
    float inv = 1.f / fmaxf(n, 1e-12f);
    *p = v * inv;
    if (lane == 0) {
        float s = as * inv;
        if (which == 0) qrow[rr] = s; else kheight[rr] = s;
    }
}

__global__ void qprobe_kernel(const float* __restrict__ qrow, float* __restrict__ qprobe)
{
    int i = blockIdx.x * 64 + threadIdx.x;
    double s = 0.0;
    for (int h = 0; h < 64; h++) s += qrow[(size_t)i * 64 + h];
    qprobe[i] = (float)s;
}

// ---------------- scores + top-k rows/cols + gather k/v ----------------
__global__ __launch_bounds__(64) void select_kernel(
    const float* __restrict__ qkv, const float* __restrict__ qprobe,
    const float* __restrict__ kheight,
    float* __restrict__ ksel, float* __restrict__ vsel)
{
    const int bh = blockIdx.x;
    const int b = bh >> 3, head = bh & 7;
    const int lane = threadIdx.x;
    __shared__ int hs[8], wsl[8];
    __shared__ float qp[32];
    if (lane < 32) qp[lane] = qprobe[bh * 32 + lane];
    __syncthreads();
    double scd = 0.0;
    for (int c = 0; c < 32; c++) scd += (double)qp[c] * kheight[((size_t)bh * 32 + c) * 64 + lane];
    float sc = (float)scd;
    for (int it = 0; it < 8; it++) {
        float v = sc; int id = lane;
        for (int off = 32; off; off >>= 1) {
            float ov = __shfl_xor(v, off); int oi = __shfl_xor(id, off);
            if (ov > v || (ov == v && oi < id)) { v = ov; id = oi; }
        }
        if (lane == 0) hs[it] = id;
        if (lane == id) sc = -3.4e38f;
    }
    __syncthreads();
    const float* kbase = qkv + ((size_t)b * 768 + 256 + head * 32) * NP;
    double sc2d = 0.0;
    for (int c = 0; c < 32; c++) {
        float kw = 0.f;
        for (int hi = 0; hi < 8; hi++)
            kw += fabsf(kbase[(size_t)c * NP + hs[hi] * 64 + lane]);
        sc2d += (double)qp[c] * kw;
    }
    float sc2 = (float)sc2d;
    for (int it = 0; it < 8; it++) {
        float v = sc2; int id = lane;
        for (int off = 32; off; off >>= 1) {
            float ov = __shfl_xor(v, off); int oi = __shfl_xor(id, off);
            if (ov > v || (ov == v && oi < id)) { v = ov; id = oi; }
        }
        if (lane == 0) wsl[it] = id;
        if (lane == id) sc2 = -3.4e38f;
    }
    __syncthreads();
    const float* vbase = qkv + ((size_t)b * 768 + 512 + head * 32) * NP;
    int hi = lane >> 3, wi = lane & 7;
    int hh = hs[hi], ww = wsl[wi];
    for (int d = 0; d < 32; d++) {
        ksel[((size_t)bh * 64 + lane) * 32 + d] = kbase[(size_t)d * NP + hh * 64 + ww];
        vsel[((size_t)bh * 64 + lane) * 32 + d] = vbase[(size_t)d * NP + hh * 64 + ww];
    }
}

// ---------------- attention: in-place over q slot; writes PACKED ctx ----------------
__global__ __launch_bounds__(256) void attn_kernel(
    float* __restrict__ qkv, const float* __restrict__ ksel, const float* __restrict__ vsel)
{
    __shared__ __align__(16) float ks[64][32];
    __shared__ __align__(16) float vs[64][32];
    int bh = blockIdx.y, b = bh >> 3, head = bh & 7;
    int t = threadIdx.x;
    const float* kb = ksel + (size_t)bh * 2048;
    const float* vb = vsel + (size_t)bh * 2048;
    for (int i = 0; i < 8; i++) {
        ((float*)ks)[t + i * 256] = kb[t + i * 256];
        ((float*)vs)[t + i * 256] = vb[t + i * 256];
    }
    __syncthreads();
    int p = blockIdx.x * 256 + t;
    float* qb = qkv + ((size_t)b * 768 + head * 32) * NP + p;
    float q[32];
    #pragma unroll
    for (int d = 0; d < 32; d++) q[d] = qb[(size_t)d * NP];
    float s[64], m = -3.4e38f;
    for (int j = 0; j < 64; j++) {
        float dot = 0.f;
        #pragma unroll
        for (int d = 0; d < 32; d++) dot += q[d] * ks[j][d];
        s[j] = dot; m = fmaxf(m, dot);
    }
    float den = 0.f;
    for (int j = 0; j < 64; j++) { float e = expf(s[j] - m); s[j] = e; den += e; }
    float o[32] = {};
    for (int j = 0; j < 64; j++) {
        float a = s[j];
        #pragma unroll
        for (int d = 0; d < 32; d++) o[d] += a * vs[j][d];
    }
    float r = 1.f / den;
    #pragma unroll
    for (int d = 0; d < 32; d++) qb[(size_t)d * NP] = packf(o[d] * r);
}

// ---------------- depthwise 3x3 on x; PACKED strided output planes ----------------
__global__ __launch_bounds__(256) void dwconv_kernel(
    const float* __restrict__ in, const float* __restrict__ w, const float* __restrict__ bias,
    float* __restrict__ out, int Cn, int sO)
{
    __shared__ __align__(16) float pl[64][64];
    int bcb = blockIdx.x;
    int b = bcb / Cn, c = bcb % Cn;
    const float* src = in + (size_t)bcb * NP;
    float* dst = out + ((size_t)b * sO + c) * NP;
    int t = threadIdx.x;
    for (int i = 0; i < 16; i++) { int pix = t + i * 256; pl[pix >> 6][pix & 63] = src[pix]; }
    float w9[9];
    #pragma unroll
    for (int k = 0; k < 9; k++) w9[k] = w[c * 9 + k];
    float bsv = bias[c];
    __syncthreads();
    for (int i = 0; i < 16; i++) {
        int pix = t + i * 256; int y = pix >> 6, xx = pix & 63;
        float acc = bsv;
        #pragma unroll
        for (int dy = 0; dy < 3; dy++) {
            int yy = y + dy - 1; if (yy < 0 || yy > 63) continue;
            #pragma unroll
            for (int dx = 0; dx < 3; dx++) {
                int x2 = xx + dx - 1; if (x2 < 0 || x2 > 63) continue;
                acc += w9[dy * 3 + dx] * pl[yy][x2];
            }
        }
        dst[pix] = packf(acc);
    }
}

// ---------------- fast gelu: A&S 7.1.26 erf (max abs err ~1.5e-7) ----------------
__device__ inline float gelu_fast(float x) {
    float z = x * 0.70710678118654752f;
    float a = fabsf(z);
    float t = 1.0f / (1.0f + 0.3275911f * a);
    float p = t * (0.254829592f + t * (-0.284496736f + t * (1.421413741f +
              t * (-1.453152027f + t * 1.061405429f))));
    float e = __expf(-a * a);
    float r = 1.0f - p * e;                 // erf(|z|)
    float erfz = copysignf(r, z);
    return 0.5f * x * (1.0f + erfz);
}

__device__ inline void block_reduce2(double& s, double& s2, double* red, int t)
{
    __syncthreads();
    red[t] = s; red[256 + t] = s2;
    __syncthreads();
    for (int st = 128; st; st >>= 1) {
        if (t < st) { red[t] += red[t + st]; red[256 + t] += red[256 + t + st]; }
        __syncthreads();
    }
    s = red[0]; s2 = red[256];
}

// ---------------- fused FF: h = gelu(IN(h)); h += gelu(IN(dwconv3(h))); PACKED out ----
__global__ __launch_bounds__(256) void ff_fused_kernel(
    float* __restrict__ h, const float* __restrict__ w, const float* __restrict__ bias)
{
    __shared__ __align__(16) float pl[64][64];
    __shared__ double red[512];
    int plane = blockIdx.x;
    int c = plane & (NFF - 1);
    size_t base = (size_t)plane * NP;
    int t = threadIdx.x;
    float v[16]; double s = 0.0, s2 = 0.0;
    for (int i = 0; i < 16; i++) { float x = h[base + t + i * 256]; v[i] = x; s += x; s2 += (double)x * x; }
    block_reduce2(s, s2, red, t);
    double mean = s * (1.0 / NP);
    double var = s2 * (1.0 / NP) - mean * mean;
    float rs = (float)(1.0 / sqrt(var + (double)CEPS));
    float mf = (float)mean;
    for (int i = 0; i < 16; i++) {
        float gx = gelu_fast((v[i] - mf) * rs);
        v[i] = gx;
        int pix = t + i * 256;
        pl[pix >> 6][pix & 63] = gx;
    }
    __syncthreads();
    float w9[9];
    #pragma unroll
    for (int k = 0; k < 9; k++) w9[k] = w[c * 9 + k];
    float bsv = bias[c];
    float tv[16]; s = 0.0; s2 = 0.0;
    for (int i = 0; i < 16; i++) {
        int pix = t + i * 256; int y = pix >> 6, xx = pix & 63;
        float acc = bsv;
        #pragma unroll
        for (int dy = 0; dy < 3; dy++) {
            int yy = y + dy - 1; if (yy < 0 || yy > 63) continue;
            #pragma unroll
            for (int dx = 0; dx < 3; dx++) {
                int x2 = xx + dx - 1; if (x2 < 0 || x2 > 63) continue;
                acc += w9[dy * 3 + dx] * pl[yy][x2];
            }
        }
        tv[i] = acc; s += acc; s2 += (double)acc * acc;
    }
    block_reduce2(s, s2, red, t);
    double mean2 = s * (1.0 / NP);
    double var2 = s2 * (1.0 / NP) - mean2 * mean2;
    float rs2 = (float)(1.0 / sqrt(var2 + (double)CEPS));
    float mf2 = (float)mean2;
    for (int i = 0; i < 16; i++) {
        int pix = t + i * 256;
        float o = v[i] + gelu_fast((tv[i] - mf2) * rs2);
        h[base + pix] = packf(o);
    }
}

// ---------------- final instance norm in place on d_out ----------------
__global__ __launch_bounds__(256) void in_final_kernel(float* __restrict__ y)
{
    __shared__ double red[512];
    size_t base = (size_t)blockIdx.x * NP;
    int t = threadIdx.x;
    float v[16]; double s = 0.0, s2 = 0.0;
    for (int i = 0; i < 16; i++) { float x = y[base + t + i * 256]; v[i] = x; s += x; s2 += (double)x * x; }
    block_reduce2(s, s2, red, t);
    double mean = s * (1.0 / NP);
    double var = s2 * (1.0 / NP) - mean * mean;
    float rs = (float)(1.0 / sqrt(var + (double)CEPS));
    float mf = (float)mean;
    for (int i = 0; i < 16; i++)
        y[base + t + i * 256] = (v[i] - mf) * rs;
}

extern "C" void kernel_launch(void* const* d_in, const int* in_sizes, int n_in,
                              void* d_out, int out_size, void* d_ws, size_t ws_size,
                              hipStream_t stream)
{
    const float* x      = (const float*)d_in[0];
    const float* g      = (const float*)d_in[1];
    const float* bc     = (const float*)d_in[2];
    const float* w_qkv  = (const float*)d_in[3];
    const float* w_out  = (const float*)d_in[4];
    const float* b_out  = (const float*)d_in[5];
    const float* w_dw   = (const float*)d_in[6];
    const float* b_dw   = (const float*)d_in[7];
    const float* w_comb = (const float*)d_in[8];
    const float* b_comb = (const float*)d_in[9];
    const float* w_ff1  = (const float*)d_in[10];
    const float* b_ff1  = (const float*)d_in[11];
    const float* w_ffdw = (const float*)d_in[12];
    const float* b_ffdw = (const float*)d_in[13];
    const float* w_ff2  = (const float*)d_in[14];
    const float* b_ff2  = (const float*)d_in[15];
    float* out = (float*)d_out;
    float* ws  = (float*)d_ws;

    const size_t S = (size_t)NB * NC * NP;   // 16,777,216 floats (64 MiB)
    float* xn    = ws;
    float* qkv   = ws + S;
    float* h1    = ws;
    float* Fbuf  = out;
    float* attnb = qkv + (size_t)256 * NP;
    float* convb = qkv + (size_t)512 * NP;
    float* qrow    = ws;
    float* qprobe  = qrow + 262144;
    float* kheight = qprobe + 4096;
    float* kselb   = kheight + 262144;
    float* vselb   = kselb + 262144;

    size_t need = 4 * S * sizeof(float);
    if (ws_size < need) {
        float val = 1024.0f + (float)(ws_size >> 20);
        diag_fill<<<(out_size + 255) / 256, 256, 0, stream>>>(out, val, out_size);
        return;
    }

    cln_kernel<<<256, 256, 0, stream>>>(x, g, bc, xn);
    gemm_mfma<false><<<dim3(16, 6, NB), 512, 0, stream>>>(xn, 256, 256, nullptr, 0, 256,
                                                          w_qkv, nullptr, nullptr, qkv, 768, 768);
    l2norm_kernel<<<131072, 256, 0, stream>>>(qkv, qrow, kheight);
    qprobe_kernel<<<64, 64, 0, stream>>>(qrow, qprobe);
    select_kernel<<<NBH, 64, 0, stream>>>(qkv, qprobe, kheight, kselb, vselb);
    attn_kernel<<<dim3(16, NBH), 256, 0, stream>>>(qkv, kselb, vselb);
    gemm_mfma<true><<<dim3(16, 2, NB), 512, 0, stream>>>(qkv, 768, 256, nullptr, 0, 256,
                                                         w_out, b_out, nullptr, attnb, 768, 256);
    dwconv_kernel<<<NB * NC, 256, 0, stream>>>(x, w_dw, b_dw, convb, NC, 768);
    gemm_mfma<true><<<dim3(16, 2, NB), 512, 0, stream>>>(attnb, 768, 256, convb, 768, 512,
                                                         w_comb, b_comb, x, Fbuf, 256, 256);
    gemm_mfma<false><<<dim3(16, 8, NB), 512, 0, stream>>>(Fbuf, 256, 256, nullptr, 0, 256,
                                                          w_ff1, b_ff1, nullptr, h1, 1024, 1024);
    ff_fused_kernel<<<NB * NFF, 256, 0, stream>>>(h1, w_ffdw, b_ffdw);
    gemm_mfma<false><<<dim3(16, 2, NB), 512, 0, stream>>>(h1, 1024, 1024, nullptr, 0, 1024,
                                                          w_ff2, b_ff2, nullptr, out, 256, 256);
    in_final_kernel<<<NB * NC, 256, 0, stream>>>(out);
}